// Round 9
// baseline (478.668 us; speedup 1.0000x reference)
//
#include <hip/hip_runtime.h>

#define N_DATA     131072
#define D_VECTOR   128
#define N_SUB      8
#define D_SUB      16
#define N_CLUSTERS 256
#define N_CODEBOOKS 64

typedef float v2f __attribute__((ext_vector_type(2)));

// ws layout in 4-byte words (~6.5 MB base; +8 MiB optional cbT2 if ws permits).
// xg[s][dst][16] (permuted-gathered x, 64 MiB) lives in d_out until decode
// overwrites it.
#define WS_LABELS 0
#define WS_PERM   (N_DATA)
#define WS_CNT    (2*N_DATA)
#define WS_CURSOR (2*N_DATA + 64)
#define WS_OFF    (2*N_DATA + 128)
#define WS_CNORM  (2*N_DATA + 256)                  // 512 rows x 256 k, numpy-order fp32
#define WS_CNSEL  (WS_CNORM + N_CODEBOOKS*N_SUB*N_CLUSTERS)
#define WS_CODES  (WS_CNSEL + 64)                   // 131072*8 bytes = 262144 words
#define WS_XN8P   (WS_CODES + 262144)               // per-(s,pos) xnorms, permuted order: 1M words = 4 MiB
#define WS_CBT2   (WS_XN8P + N_SUB*N_DATA)          // optional: row-major codebook for decode
#define CBT2_WORDS (N_CODEBOOKS*N_SUB*N_CLUSTERS*D_SUB)   // 2,097,152 words = 8 MiB

// ---------------------------------------------------------------- precompute
// cnorm = np.sum(cb*cb, axis=2) (sequential d, separate mul/add). If cbT2 is
// non-null, also emit the row-major decode codebook cbT2[row][k][d] so decode
// reads ONE 64B line per (point,s).
__global__ __launch_bounds__(256) void pq_precompute(
    const float* __restrict__ cb, const float* __restrict__ sel,
    float* __restrict__ cnorm_cb, float* __restrict__ cnorm_sel,
    float* __restrict__ cbT2, int* __restrict__ cnt)
{
    int row = blockIdx.x;                 // 0..511 = l*8+s
    int k   = threadIdx.x;                // 0..255
    const float* p = cb + (size_t)row * (D_SUB * N_CLUSTERS) + k;
    float vals[D_SUB];
    float sum = 0.f;
#pragma unroll
    for (int d = 0; d < D_SUB; d++) {
        float v = p[(size_t)d * N_CLUSTERS];
        vals[d] = v;
        sum = __fadd_rn(sum, __fmul_rn(v, v));
    }
    int idx = row * 256 + k;
    cnorm_cb[idx] = sum;
    if (cbT2) {                           // uniform branch
        float4* dst = (float4*)(cbT2 + ((size_t)row << 12) + ((size_t)k << 4));
#pragma unroll
        for (int q = 0; q < 4; q++)
            dst[q] = make_float4(vals[4*q], vals[4*q+1], vals[4*q+2], vals[4*q+3]);
    }
    if (idx < N_CODEBOOKS) {
        float s2 = 0.f;
        for (int d = 0; d < D_VECTOR; d++) {
            float v = sel[d * N_CODEBOOKS + idx];
            s2 = __fadd_rn(s2, __fmul_rn(v, v));
        }
        cnorm_sel[idx] = s2;
        cnt[idx] = 0;
    }
}

// ---------------------------------------------------------------- stage 1: labels
__global__ __launch_bounds__(256, 4) void pq_labels2(
    const float* __restrict__ x, const float* __restrict__ sel,
    const float* __restrict__ cnorm_sel,
    int* __restrict__ labels, int* __restrict__ cnt)
{
    __shared__ int hist[N_CODEBOOKS];
    int tid = threadIdx.x;
    if (tid < N_CODEBOOKS) hist[tid] = 0;
    __syncthreads();

    int n = blockIdx.x * 256 + tid;

    v2f acc[32];
#pragma unroll
    for (int lp = 0; lp < 32; lp++) acc[lp] = (v2f){0.f, 0.f};

    float xn = 0.f;
    for (int d = 0; d < D_VECTOR; d++) {
        float xv = x[(size_t)d * N_DATA + n];        // coalesced
        xn = __fadd_rn(xn, __fmul_rn(xv, xv));       // sequential d: numpy-exact
        v2f xv2 = (v2f){xv, xv};
        const v2f* sp = (const v2f*)(sel + d * N_CODEBOOKS);  // uniform
#pragma unroll
        for (int lp = 0; lp < 32; lp++)
            acc[lp] = __builtin_elementwise_fma(xv2, sp[lp], acc[lp]);  // v_pk_fma_f32
    }

    float best = 1e30f;
    int   bl = 0;
#pragma unroll
    for (int lp = 0; lp < 32; lp++) {
        float dx = __fadd_rn(__fsub_rn(xn, __fmul_rn(2.0f, acc[lp].x)), cnorm_sel[2*lp]);
        float dy = __fadd_rn(__fsub_rn(xn, __fmul_rn(2.0f, acc[lp].y)), cnorm_sel[2*lp + 1]);
        if (dx < best) { best = dx; bl = 2*lp; }
        if (dy < best) { best = dy; bl = 2*lp + 1; }
    }
    labels[n] = bl;
    atomicAdd(&hist[bl], 1);
    __syncthreads();
    if (tid < N_CODEBOOKS) atomicAdd(&cnt[tid], hist[tid]);
}

// ---------------------------------------------------------------- scan (1 wave)
__global__ void pq_scan(const int* __restrict__ cnt, int* __restrict__ off, int* __restrict__ cursor)
{
    int tid = threadIdx.x;
    int v = cnt[tid];
    int inc = v;
#pragma unroll
    for (int sft = 1; sft < 64; sft <<= 1) {
        int o = __shfl_up(inc, sft, 64);
        if (tid >= sft) inc += o;
    }
    int exc = inc - v;
    off[tid] = exc;
    cursor[tid] = exc;
    if (tid == 63) off[64] = inc;
}

// ---------------------------------------------------------------- counting-sort scatter + permute-gather
// perm entries are PACKED: (n << 6) | label. Copies each point's 8 subvectors
// into xg[s][dst][16] (dense; encode reads one 64B line per point) and writes
// the per-(s,point) xnorm into xn8p[s][dst] with the EXACT numpy reduction
// order (sequential d, separate mul/add) so encode can load it bit-identically.
__global__ __launch_bounds__(256) void pq_scatter(
    const float* __restrict__ x, const int* __restrict__ labels,
    int* __restrict__ cursor, unsigned int* __restrict__ perm,
    float* __restrict__ xg, float* __restrict__ xn8p)
{
    __shared__ int lcnt[N_CODEBOOKS];
    __shared__ int lbase[N_CODEBOOKS];
    int tid = threadIdx.x;
    if (tid < N_CODEBOOKS) lcnt[tid] = 0;
    __syncthreads();
    int base = blockIdx.x * 1024;
    int lv[4], slot[4];
#pragma unroll
    for (int i = 0; i < 4; i++) {
        int n = base + i * 256 + tid;
        int l = labels[n];
        lv[i] = l;
        slot[i] = atomicAdd(&lcnt[l], 1);
    }
    __syncthreads();
    if (tid < N_CODEBOOKS) lbase[tid] = atomicAdd(&cursor[tid], lcnt[tid]);
    __syncthreads();
#pragma unroll
    for (int i = 0; i < 4; i++) {
        int n = base + i * 256 + tid;
        int dst = lbase[lv[i]] + slot[i];
        perm[dst] = ((unsigned)n << 6) | (unsigned)lv[i];
#pragma unroll
        for (int s = 0; s < N_SUB; s++) {
            float v[D_SUB];
#pragma unroll
            for (int d = 0; d < D_SUB; d++)
                v[d] = x[(size_t)(s * D_SUB + d) * N_DATA + n];   // coalesced
            float4* o = (float4*)(xg + (((size_t)s * N_DATA + (size_t)dst) << 4));
            o[0] = make_float4(v[0],  v[1],  v[2],  v[3]);
            o[1] = make_float4(v[4],  v[5],  v[6],  v[7]);
            o[2] = make_float4(v[8],  v[9],  v[10], v[11]);
            o[3] = make_float4(v[12], v[13], v[14], v[15]);
            float xn = 0.f;
#pragma unroll
            for (int d = 0; d < D_SUB; d++)
                xn = __fadd_rn(xn, __fmul_rn(v[d], v[d]));        // numpy order
            xn8p[(size_t)s * N_DATA + (size_t)dst] = xn;
        }
    }
}

// DPP min step: v = min(v, v_from_lane(ctrl)). Invalid-source lanes keep v (old).
template<int CTRL>
__device__ __forceinline__ float dppmin(float v)
{
    int t = __builtin_amdgcn_update_dpp(__float_as_int(v), __float_as_int(v),
                                        CTRL, 0xF, 0xF, false);
    return fminf(v, __int_as_float(t));
}

// ---------------------------------------------------------------- stage 2: PQ encode v13 (lane = k)
// Wave = 64 consecutive perm positions for one s, processed one point per
// iteration; lane L holds clusters [4L,4L+4) x 16 d in VGPRs, reloaded only
// on (uniform) label change -> ZERO codebook fetches in the k-loop (the cost
// all three per-k delivery mechanisms paid). Per point: x row + xnorm come
// from pos-indexed xg/xn8p (uniform address, 1-deep ping-pong prefetch);
// distances via packed mul/add (contract off, exact numpy order); argmin via
// per-lane min4 + DPP butterfly + ballot (lowest lane & lowest j on ties =
// numpy first-occurrence; NaN-free, +/-0 equal). codes accumulated per-lane
// (lane==i select), one scattered byte store per wave at the end.
// __launch_bounds__(256,3): <=170 VGPR so cbA/cbB stay RESIDENT (v4/v5's 64-VGPR
// remat trap avoided); ~140 VGPR expected, 12 waves/CU.
__global__ __launch_bounds__(256, 3) void pq_encode14(
    const float* __restrict__ xg, const float* __restrict__ cb,
    const float* __restrict__ cnorm_cb, const float* __restrict__ xn8p,
    const unsigned int* __restrict__ perm, unsigned char* __restrict__ codes)
{
    int tid  = threadIdx.x;
    int lane = tid & 63;
    int w    = tid >> 6;
    int s    = blockIdx.x & 7;
    int base = (int)(blockIdx.x >> 3) * 256 + w * 64;

    int lcur = -1;
    v2f cbA[D_SUB], cbB[D_SUB];
    v2f cnA = (v2f){0.f, 0.f}, cnB = (v2f){0.f, 0.f};
    int mycode = 0, myn = 0;

    // pipeline prologue: packed word + x row + xn for point 0; packed word for point 1
    unsigned pkc = perm[base];
    float4 xbuf[2][4];
    float  xnbuf[2];
    {
        const float4* xp = (const float4*)(xg + (((size_t)s * N_DATA + (size_t)base) << 4));
        xbuf[0][0] = xp[0]; xbuf[0][1] = xp[1]; xbuf[0][2] = xp[2]; xbuf[0][3] = xp[3];
        xnbuf[0] = xn8p[(size_t)s * N_DATA + (size_t)base];
    }
    unsigned pkn = perm[base + 1];

#pragma unroll 2
    for (int i = 0; i < 64; i++) {
        const int cur = i & 1;
        const int nxt = cur ^ 1;
        unsigned pk = pkc;
        int n = (int)(pk >> 6), l = (int)(pk & 63u);

        // prefetch point i+1's x row + xn (pos-indexed: no dependence on perm)
        if (i < 63) {
            int posn = base + i + 1;
            const float4* xq = (const float4*)(xg + (((size_t)s * N_DATA + (size_t)posn) << 4));
            xbuf[nxt][0] = xq[0]; xbuf[nxt][1] = xq[1];
            xbuf[nxt][2] = xq[2]; xbuf[nxt][3] = xq[3];
            xnbuf[nxt] = xn8p[(size_t)s * N_DATA + (size_t)posn];
        }
        pkc = pkn;
        if (i < 62) pkn = perm[base + i + 2];

        if (l != lcur) {                   // uniform branch; ~1-2x per 64 points
            lcur = l;
            const float* cbs = cb + (size_t)(l * N_SUB + s) * (D_SUB * N_CLUSTERS);
#pragma unroll
            for (int d = 0; d < D_SUB; d++) {
                float4 v = *(const float4*)(cbs + (size_t)d * N_CLUSTERS + lane * 4);
                cbA[d] = (v2f){v.x, v.y};
                cbB[d] = (v2f){v.z, v.w};
            }
            float4 c = *(const float4*)(cnorm_cb + (size_t)(l * N_SUB + s) * N_CLUSTERS + lane * 4);
            cnA = (v2f){c.x, c.y};
            cnB = (v2f){c.z, c.w};
        }

        float4 x0 = xbuf[cur][0], x1 = xbuf[cur][1], x2 = xbuf[cur][2], x3 = xbuf[cur][3];
        float xs[D_SUB] = { x0.x, x0.y, x0.z, x0.w, x1.x, x1.y, x1.z, x1.w,
                            x2.x, x2.y, x2.z, x2.w, x3.x, x3.y, x3.z, x3.w };
        float xn = xnbuf[cur];             // precomputed, bit-identical order

        float m; int j;
        {
#pragma clang fp contract(off)
            v2f a0 = (v2f){0.f, 0.f}, a1 = (v2f){0.f, 0.f};
#pragma unroll
            for (int d = 0; d < D_SUB; d++) {
                v2f xv = (v2f){xs[d], xs[d]};
                a0 = a0 + xv * cbA[d];     // v_pk_mul + v_pk_add, exact order
                a1 = a1 + xv * cbB[d];
            }
            v2f xnv  = (v2f){xn, xn};
            v2f twov = (v2f){2.f, 2.f};
            v2f d0 = (xnv - twov * a0) + cnA;   // ((xn - 2*acc) + cn), rounded per op
            v2f d1 = (xnv - twov * a1) + cnB;

            // per-lane min of 4 with numpy first-tie (== priority low j; +/-0 equal)
            m = fminf(fminf(d0.x, d0.y), fminf(d1.x, d1.y));
            j = (d1.x == m) ? 2 : 3;
            j = (d0.y == m) ? 1 : j;
            j = (d0.x == m) ? 0 : j;
        }

        // cross-lane min via DPP: shr 1/2/4/8 -> lane15 of each row holds row
        // min; bcast15 merges row pairs, bcast31 merges halves -> lane 63.
        float g = m;
        g = dppmin<0x111>(g);   // row_shr:1
        g = dppmin<0x112>(g);   // row_shr:2
        g = dppmin<0x114>(g);   // row_shr:4
        g = dppmin<0x118>(g);   // row_shr:8
        g = dppmin<0x142>(g);   // row_bcast:15
        g = dppmin<0x143>(g);   // row_bcast:31
        float gmin = __int_as_float(__builtin_amdgcn_readlane(__float_as_int(g), 63));

        unsigned long long bal = __ballot(m == gmin);
        int winner = (int)(__ffsll((long long)bal) - 1);   // lowest lane = lowest k
        int myk = (lane << 2) | j;
        int kwin = __builtin_amdgcn_readlane(myk, winner); // uniform
        bool selp = (lane == i);
        mycode = selp ? kwin : mycode;
        myn    = selp ? n    : myn;
    }
    codes[((size_t)myn << 3) | s] = (unsigned char)mycode;
}

// ---------------------------------------------------------------- decode (fast): 1 line per (n,s)
__global__ __launch_bounds__(256) void pq_decode_fast(
    const float* __restrict__ cbT2, const int* __restrict__ labels,
    const unsigned char* __restrict__ codes, float* __restrict__ out)
{
    int s = blockIdx.x & 7;
    int n = (blockIdx.x >> 3) * 256 + threadIdx.x;
    int l = labels[n];
    int k = codes[(size_t)n * N_SUB + s];
    const float4* p = (const float4*)(cbT2 + ((size_t)(l * N_SUB + s) << 12) + ((size_t)k << 4));
    float4 a = p[0], b = p[1], c = p[2], d = p[3];
    float v[D_SUB] = { a.x, a.y, a.z, a.w, b.x, b.y, b.z, b.w,
                       c.x, c.y, c.z, c.w, d.x, d.y, d.z, d.w };
#pragma unroll
    for (int dd = 0; dd < D_SUB; dd++)
        out[(size_t)(s * D_SUB + dd) * N_DATA + n] = v[dd];   // coalesced
}

// ---------------------------------------------------------------- decode (fallback): strided column gather
__global__ __launch_bounds__(256) void pq_decode(
    const float* __restrict__ cb, const int* __restrict__ labels,
    const unsigned char* __restrict__ codes, float* __restrict__ out)
{
    int s = blockIdx.x & 7;
    int n = (blockIdx.x >> 3) * 256 + threadIdx.x;
    int l = labels[n];
    int k = codes[(size_t)n * N_SUB + s];
    const float* base = cb + ((size_t)(l * N_SUB + s) * D_SUB) * N_CLUSTERS + k;
#pragma unroll
    for (int dd = 0; dd < D_SUB; dd++)
        out[(size_t)(s * D_SUB + dd) * N_DATA + n] = base[(size_t)dd * N_CLUSTERS];
}

// ---------------------------------------------------------------- launcher
extern "C" void kernel_launch(void* const* d_in, const int* in_sizes, int n_in,
                              void* d_out, int out_size, void* d_ws, size_t ws_size,
                              hipStream_t stream)
{
    (void)in_sizes; (void)n_in; (void)out_size;
    const float* x   = (const float*)d_in[0];
    const float* cb  = (const float*)d_in[1];
    const float* sel = (const float*)d_in[2];
    float* out = (float*)d_out;

    int*   wsi    = (int*)d_ws;
    float* wsf    = (float*)d_ws;
    int*   labels = wsi + WS_LABELS;
    unsigned int* perm = (unsigned int*)(wsi + WS_PERM);
    int*   cnt    = wsi + WS_CNT;
    int*   cursor = wsi + WS_CURSOR;
    int*   off    = wsi + WS_OFF;
    float* cnorm  = wsf + WS_CNORM;
    float* cnsel  = wsf + WS_CNSEL;
    unsigned char* codes = (unsigned char*)(wsi + WS_CODES);
    float* xn8p   = wsf + WS_XN8P;     // within the confirmed-available ~11 MiB

    // row-major decode codebook only if the workspace is big enough (~14.6 MiB)
    bool big = ws_size >= (size_t)(WS_CBT2 + CBT2_WORDS) * 4u;
    float* cbT2 = big ? (wsf + WS_CBT2) : (float*)nullptr;

    // permuted-gathered x (64 MiB) lives in d_out; decode overwrites it fully
    float* xg = out;

    hipLaunchKernelGGL(pq_precompute, dim3(512), dim3(256), 0, stream, cb, sel, cnorm, cnsel, cbT2, cnt);
    hipLaunchKernelGGL(pq_labels2, dim3(N_DATA / 256), dim3(256), 0, stream, x, sel, cnsel, labels, cnt);
    hipLaunchKernelGGL(pq_scan, dim3(1), dim3(64), 0, stream, cnt, off, cursor);
    hipLaunchKernelGGL(pq_scatter, dim3(N_DATA / 1024), dim3(256), 0, stream, x, labels, cursor, perm, xg, xn8p);
    hipLaunchKernelGGL(pq_encode14, dim3((N_DATA / 256) * N_SUB), dim3(256), 0, stream,
                       xg, cb, cnorm, xn8p, perm, codes);
    if (big)
        hipLaunchKernelGGL(pq_decode_fast, dim3((N_DATA / 256) * N_SUB), dim3(256), 0, stream,
                           cbT2, labels, codes, out);
    else
        hipLaunchKernelGGL(pq_decode, dim3((N_DATA / 256) * N_SUB), dim3(256), 0, stream,
                           cb, labels, codes, out);
}

// Round 10
// 406.398 us; speedup vs baseline: 1.1778x; 1.1778x over previous
//
#include <hip/hip_runtime.h>

#define N_DATA     131072
#define D_VECTOR   128
#define N_SUB      8
#define D_SUB      16
#define N_CLUSTERS 256
#define N_CODEBOOKS 64

typedef float v2f __attribute__((ext_vector_type(2)));

// ws layout in 4-byte words (~2.5 MB base; +8 MB optional cbT2 if ws permits).
// xg[s][dst][16] (permuted-gathered x, 64 MiB) lives in d_out until decode
// overwrites it.
#define WS_LABELS 0
#define WS_PERM   (N_DATA)
#define WS_CNT    (2*N_DATA)
#define WS_CURSOR (2*N_DATA + 64)
#define WS_OFF    (2*N_DATA + 128)
#define WS_CNORM  (2*N_DATA + 256)                  // 512 rows x 256 k, numpy-order fp32
#define WS_CNSEL  (WS_CNORM + N_CODEBOOKS*N_SUB*N_CLUSTERS)
#define WS_CODES  (WS_CNSEL + 64)                   // 131072*8 bytes = 262144 words
#define WS_CBT2   (WS_CODES + 262144)               // optional: row-major codebook for decode
#define CBT2_WORDS (N_CODEBOOKS*N_SUB*N_CLUSTERS*D_SUB)   // 2,097,152 words = 8 MiB

// ---------------------------------------------------------------- precompute
// cnorm = np.sum(cb*cb, axis=2) (sequential d, separate mul/add). If cbT2 is
// non-null, also emit a row-major codebook cbT2[row][k][d] = cb[row][d][k]
// (row = l*8+s) so decode reads ONE 64B line per (point,s) instead of a
// 16-element strided column.
__global__ __launch_bounds__(256) void pq_precompute(
    const float* __restrict__ cb, const float* __restrict__ sel,
    float* __restrict__ cnorm_cb, float* __restrict__ cnorm_sel,
    float* __restrict__ cbT2, int* __restrict__ cnt)
{
    int row = blockIdx.x;                 // 0..511 = l*8+s
    int k   = threadIdx.x;                // 0..255
    const float* p = cb + (size_t)row * (D_SUB * N_CLUSTERS) + k;
    float vals[D_SUB];
    float sum = 0.f;
#pragma unroll
    for (int d = 0; d < D_SUB; d++) {
        float v = p[(size_t)d * N_CLUSTERS];
        vals[d] = v;
        sum = __fadd_rn(sum, __fmul_rn(v, v));
    }
    int idx = row * 256 + k;
    cnorm_cb[idx] = sum;
    if (cbT2) {                           // uniform branch
        float4* dst = (float4*)(cbT2 + ((size_t)row << 12) + ((size_t)k << 4));
#pragma unroll
        for (int q = 0; q < 4; q++)
            dst[q] = make_float4(vals[4*q], vals[4*q+1], vals[4*q+2], vals[4*q+3]);
    }
    if (idx < N_CODEBOOKS) {
        float s2 = 0.f;
        for (int d = 0; d < D_VECTOR; d++) {
            float v = sel[d * N_CODEBOOKS + idx];
            s2 = __fadd_rn(s2, __fmul_rn(v, v));
        }
        cnorm_sel[idx] = s2;
        cnt[idx] = 0;
    }
}

// ---------------------------------------------------------------- stage 1: labels
__global__ __launch_bounds__(256, 4) void pq_labels2(
    const float* __restrict__ x, const float* __restrict__ sel,
    const float* __restrict__ cnorm_sel,
    int* __restrict__ labels, int* __restrict__ cnt)
{
    __shared__ int hist[N_CODEBOOKS];
    int tid = threadIdx.x;
    if (tid < N_CODEBOOKS) hist[tid] = 0;
    __syncthreads();

    int n = blockIdx.x * 256 + tid;

    v2f acc[32];
#pragma unroll
    for (int lp = 0; lp < 32; lp++) acc[lp] = (v2f){0.f, 0.f};

    float xn = 0.f;
    for (int d = 0; d < D_VECTOR; d++) {
        float xv = x[(size_t)d * N_DATA + n];        // coalesced
        xn = __fadd_rn(xn, __fmul_rn(xv, xv));       // sequential d: numpy-exact
        v2f xv2 = (v2f){xv, xv};
        const v2f* sp = (const v2f*)(sel + d * N_CODEBOOKS);  // uniform
#pragma unroll
        for (int lp = 0; lp < 32; lp++)
            acc[lp] = __builtin_elementwise_fma(xv2, sp[lp], acc[lp]);  // v_pk_fma_f32
    }

    float best = 1e30f;
    int   bl = 0;
#pragma unroll
    for (int lp = 0; lp < 32; lp++) {
        float dx = __fadd_rn(__fsub_rn(xn, __fmul_rn(2.0f, acc[lp].x)), cnorm_sel[2*lp]);
        float dy = __fadd_rn(__fsub_rn(xn, __fmul_rn(2.0f, acc[lp].y)), cnorm_sel[2*lp + 1]);
        if (dx < best) { best = dx; bl = 2*lp; }
        if (dy < best) { best = dy; bl = 2*lp + 1; }
    }
    labels[n] = bl;
    atomicAdd(&hist[bl], 1);
    __syncthreads();
    if (tid < N_CODEBOOKS) atomicAdd(&cnt[tid], hist[tid]);
}

// ---------------------------------------------------------------- scan (1 wave)
__global__ void pq_scan(const int* __restrict__ cnt, int* __restrict__ off, int* __restrict__ cursor)
{
    int tid = threadIdx.x;
    int v = cnt[tid];
    int inc = v;
#pragma unroll
    for (int sft = 1; sft < 64; sft <<= 1) {
        int o = __shfl_up(inc, sft, 64);
        if (tid >= sft) inc += o;
    }
    int exc = inc - v;
    off[tid] = exc;
    cursor[tid] = exc;
    if (tid == 63) off[64] = inc;
}

// ---------------------------------------------------------------- counting-sort scatter + permute-gather
// perm entries are PACKED: (n << 6) | label. Additionally copies each point's
// 8 subvectors into xg[s][dst][16] (exact fp32 copy): x reads are coalesced
// across threads (consecutive n), xg writes are dense scattered 64B lines.
// Encode then reads xg perfectly coalesced with zero gather.
__global__ __launch_bounds__(256) void pq_scatter(
    const float* __restrict__ x, const int* __restrict__ labels,
    int* __restrict__ cursor, unsigned int* __restrict__ perm,
    float* __restrict__ xg)
{
    __shared__ int lcnt[N_CODEBOOKS];
    __shared__ int lbase[N_CODEBOOKS];
    int tid = threadIdx.x;
    if (tid < N_CODEBOOKS) lcnt[tid] = 0;
    __syncthreads();
    int base = blockIdx.x * 1024;
    int lv[4], slot[4];
#pragma unroll
    for (int i = 0; i < 4; i++) {
        int n = base + i * 256 + tid;
        int l = labels[n];
        lv[i] = l;
        slot[i] = atomicAdd(&lcnt[l], 1);
    }
    __syncthreads();
    if (tid < N_CODEBOOKS) lbase[tid] = atomicAdd(&cursor[tid], lcnt[tid]);
    __syncthreads();
#pragma unroll
    for (int i = 0; i < 4; i++) {
        int n = base + i * 256 + tid;
        int dst = lbase[lv[i]] + slot[i];
        perm[dst] = ((unsigned)n << 6) | (unsigned)lv[i];
#pragma unroll
        for (int s = 0; s < N_SUB; s++) {
            float v[D_SUB];
#pragma unroll
            for (int d = 0; d < D_SUB; d++)
                v[d] = x[(size_t)(s * D_SUB + d) * N_DATA + n];   // coalesced
            float4* o = (float4*)(xg + (((size_t)s * N_DATA + (size_t)dst) << 4));
            o[0] = make_float4(v[0],  v[1],  v[2],  v[3]);
            o[1] = make_float4(v[4],  v[5],  v[6],  v[7]);
            o[2] = make_float4(v[8],  v[9],  v[10], v[11]);
            o[3] = make_float4(v[12], v[13], v[14], v[15]);
        }
    }
}

// ---------------------------------------------------------------- stage 2: PQ encode (v8 structure, proven 252us)
// Lane = one point, in perm order: x reads from xg are fully coalesced.
// Codebook is streamed straight from cb via wave-uniform scalar loads.
// Boundary waves (~3%) use the ballot multipass. Arithmetic per (point,k)
// unchanged: sequential-d separate mul/add (contract off),
// dist = (xn - 2*acc) + cn. Argmin: per-component chains (even/odd k),
// ascending kkp strict <, merged with the exact lower-k tie rule -> numpy
// first-occurrence. Distances NaN-free.
// SOLE change vs the 430us round-4 version: kkp loop unroll 2 -> 4, batching
// ~4x34 data SGPRs of s_loads per group so the scalar-load latency of group
// g+1 hides under group g's ~82cy of VALU (SGPR budget 256, no vector-typed
// staging arrays -> no v9-style spill path).
__global__ __launch_bounds__(256, 8) void pq_encode9(
    const float* __restrict__ xg, const float* __restrict__ cb,
    const float* __restrict__ cnorm_cb, const unsigned int* __restrict__ perm,
    unsigned char* __restrict__ codes)
{
    int tid = threadIdx.x;
    int s   = blockIdx.x & 7;
    int pos = (int)(blockIdx.x >> 3) * 256 + tid;
    unsigned pk = perm[pos];
    int n = (int)(pk >> 6);
    int l = (int)(pk & 63u);

    const float4* xp = (const float4*)(xg + (((size_t)s * N_DATA + (size_t)pos) << 4));
    float4 x0 = xp[0], x1 = xp[1], x2 = xp[2], x3 = xp[3];
    float xs[D_SUB] = { x0.x, x0.y, x0.z, x0.w, x1.x, x1.y, x1.z, x1.w,
                        x2.x, x2.y, x2.z, x2.w, x3.x, x3.y, x3.z, x3.w };

    // xnorm: numpy strided reduction (sequential d, separate mul/add)
    float xn = 0.f;
#pragma unroll
    for (int d = 0; d < D_SUB; d++)
        xn = __fadd_rn(xn, __fmul_rn(xs[d], xs[d]));

    v2f xs2[D_SUB];
#pragma unroll
    for (int d = 0; d < D_SUB; d++) xs2[d] = (v2f){xs[d], xs[d]};
    const v2f xnv  = (v2f){xn, xn};
    const v2f twov = (v2f){2.f, 2.f};

    int bestk = 0;
    bool done = false;
    while (true) {
        unsigned long long todo = __ballot(!done);
        if (!todo) break;
        int src  = (int)(__ffsll((long long)todo) - 1);
        int lcur = __builtin_amdgcn_readlane(l, src);      // uniform label for this pass

        const float* cbs = cb       + ((size_t)(lcur * N_SUB + s) << 12);  // [d][k] row -> s_load
        const float* cns = cnorm_cb + ((size_t)(lcur * N_SUB + s) << 8);   // uniform -> s_load

        float bx = 1e30f, by = 1e30f;
        int   kx = 0, ky = 0;
        {
#pragma clang fp contract(off)
#pragma unroll 4
            for (int kkp = 0; kkp < N_CLUSTERS / 2; kkp++) {
                v2f cn2 = *(const v2f*)(cns + (kkp << 1));
                v2f a = (v2f){0.f, 0.f};
#pragma unroll
                for (int d = 0; d < D_SUB; d++) {
                    v2f c = *(const v2f*)(cbs + (size_t)(d * N_CLUSTERS) + (kkp << 1));
                    a = a + xs2[d] * c;          // v_pk_mul + v_pk_add, exact order
                }
                v2f dd = (xnv - twov * a) + cn2;
                if (dd.x < bx) { bx = dd.x; kx = kkp; }
                if (dd.y < by) { by = dd.y; ky = kkp; }
            }
        }
        // merge even/odd chains: strictly-better or equal-with-lower-k picks odd
        int bk = 2 * kx;
        { int kodd = 2 * ky + 1; if (by < bx || (by == bx && kodd < bk)) bk = kodd; }

        if (!done && l == lcur) { bestk = bk; done = true; }
    }
    codes[((size_t)n << 3) | s] = (unsigned char)bestk;
}

// ---------------------------------------------------------------- decode (fast): 1 line per (n,s)
__global__ __launch_bounds__(256) void pq_decode_fast(
    const float* __restrict__ cbT2, const int* __restrict__ labels,
    const unsigned char* __restrict__ codes, float* __restrict__ out)
{
    int s = blockIdx.x & 7;
    int n = (blockIdx.x >> 3) * 256 + threadIdx.x;
    int l = labels[n];
    int k = codes[(size_t)n * N_SUB + s];
    const float4* p = (const float4*)(cbT2 + ((size_t)(l * N_SUB + s) << 12) + ((size_t)k << 4));
    float4 a = p[0], b = p[1], c = p[2], d = p[3];
    float v[D_SUB] = { a.x, a.y, a.z, a.w, b.x, b.y, b.z, b.w,
                       c.x, c.y, c.z, c.w, d.x, d.y, d.z, d.w };
#pragma unroll
    for (int dd = 0; dd < D_SUB; dd++)
        out[(size_t)(s * D_SUB + dd) * N_DATA + n] = v[dd];   // coalesced
}

// ---------------------------------------------------------------- decode (fallback): strided column gather
__global__ __launch_bounds__(256) void pq_decode(
    const float* __restrict__ cb, const int* __restrict__ labels,
    const unsigned char* __restrict__ codes, float* __restrict__ out)
{
    int s = blockIdx.x & 7;
    int n = (blockIdx.x >> 3) * 256 + threadIdx.x;
    int l = labels[n];
    int k = codes[(size_t)n * N_SUB + s];
    const float* base = cb + ((size_t)(l * N_SUB + s) * D_SUB) * N_CLUSTERS + k;
#pragma unroll
    for (int dd = 0; dd < D_SUB; dd++)
        out[(size_t)(s * D_SUB + dd) * N_DATA + n] = base[(size_t)dd * N_CLUSTERS];
}

// ---------------------------------------------------------------- launcher
extern "C" void kernel_launch(void* const* d_in, const int* in_sizes, int n_in,
                              void* d_out, int out_size, void* d_ws, size_t ws_size,
                              hipStream_t stream)
{
    (void)in_sizes; (void)n_in; (void)out_size;
    const float* x   = (const float*)d_in[0];
    const float* cb  = (const float*)d_in[1];
    const float* sel = (const float*)d_in[2];
    float* out = (float*)d_out;

    int*   wsi    = (int*)d_ws;
    float* wsf    = (float*)d_ws;
    int*   labels = wsi + WS_LABELS;
    unsigned int* perm = (unsigned int*)(wsi + WS_PERM);
    int*   cnt    = wsi + WS_CNT;
    int*   cursor = wsi + WS_CURSOR;
    int*   off    = wsi + WS_OFF;
    float* cnorm  = wsf + WS_CNORM;
    float* cnsel  = wsf + WS_CNSEL;
    unsigned char* codes = (unsigned char*)(wsi + WS_CODES);

    // row-major decode codebook only if the workspace is big enough (~10.5 MiB)
    bool big = ws_size >= (size_t)(WS_CBT2 + CBT2_WORDS) * 4u;
    float* cbT2 = big ? (wsf + WS_CBT2) : (float*)nullptr;

    // permuted-gathered x (64 MiB) lives in d_out; decode overwrites it fully
    float* xg = out;

    hipLaunchKernelGGL(pq_precompute, dim3(512), dim3(256), 0, stream, cb, sel, cnorm, cnsel, cbT2, cnt);
    hipLaunchKernelGGL(pq_labels2, dim3(N_DATA / 256), dim3(256), 0, stream, x, sel, cnsel, labels, cnt);
    hipLaunchKernelGGL(pq_scan, dim3(1), dim3(64), 0, stream, cnt, off, cursor);
    hipLaunchKernelGGL(pq_scatter, dim3(N_DATA / 1024), dim3(256), 0, stream, x, labels, cursor, perm, xg);
    hipLaunchKernelGGL(pq_encode9, dim3((N_DATA / 256) * N_SUB), dim3(256), 0, stream,
                       xg, cb, cnorm, perm, codes);
    if (big)
        hipLaunchKernelGGL(pq_decode_fast, dim3((N_DATA / 256) * N_SUB), dim3(256), 0, stream,
                           cbT2, labels, codes, out);
    else
        hipLaunchKernelGGL(pq_decode, dim3((N_DATA / 256) * N_SUB), dim3(256), 0, stream,
                           cb, labels, codes, out);
}